// Round 18
// baseline (468.541 us; speedup 1.0000x reference)
//
#include <hip/hip_runtime.h>
#include <math.h>

#define NHEADS 8
#define BATCH  256
#define HWTOK  196
#define MTOT   50176          // 1024 windows * 49

#define BM 128
#define BN 128
#define BK 64

typedef short bfrag8 __attribute__((ext_vector_type(8)));
typedef float ffrag4 __attribute__((ext_vector_type(4)));

// ---------------------------------------------------------------------------
__device__ __forceinline__ unsigned short f2bf(float f) {
  union { float f; unsigned u; } v; v.f = f;
  unsigned r = v.u + 0x7fffu + ((v.u >> 16) & 1u);   // RNE
  return (unsigned short)(r >> 16);
}
__device__ __forceinline__ float bf2f(unsigned short b) {
  union { unsigned u; float f; } v; v.u = ((unsigned)b) << 16;
  return v.f;
}
__device__ __forceinline__ float bflo(unsigned u) {
  union { unsigned x; float f; } v; v.x = u << 16; return v.f;
}
__device__ __forceinline__ float bfhi(unsigned u) {
  union { unsigned x; float f; } v; v.x = u & 0xffff0000u; return v.f;
}
__device__ __forceinline__ unsigned cvtpk(float a, float b) {
  unsigned r;
  asm("v_cvt_pk_bf16_f32 %0, %1, %2" : "=v"(r) : "v"(a), "v"(b));
  return r;
}
// GELU exact-erf (A&S 7.1.26, |err|<=1.5e-7) with fast rcp
__device__ __forceinline__ float gelu_fast(float x) {
  float ax = fabsf(x);
  float z = ax * 0.70710678118654752f;
  float t = __builtin_amdgcn_rcpf(fmaf(z, 0.3275911f, 1.0f));
  float y = t * (0.254829592f +
            t * (-0.284496736f +
            t * (1.421413741f +
            t * (-1.453152027f +
            t * 1.061405429f))));
  float e2 = __expf(-z * z);
  float erfv = fmaf(-y, e2, 1.0f);
  return 0.5f * fmaf(ax, erfv, x);
}
__device__ __forceinline__ int window_reverse_row(int m) {
  int widx = m / 49, pos = m % 49;
  int b = widx >> 2, wh = (widx >> 1) & 1, ww = widx & 1;
  int i = pos / 7, j = pos % 7;
  return b * 196 + (wh * 7 + i) * 14 + (ww * 7 + j);
}

__device__ __forceinline__ void gload16(const void* g, void* l) {
  __builtin_amdgcn_global_load_lds(
      (const __attribute__((address_space(1))) void*)g,
      (__attribute__((address_space(3))) void*)l, 16, 0, 0);
}

// bijective XCD-chunked swizzle (identity when grid not divisible by 8)
__device__ __forceinline__ int xcd_swz() {
  if (gridDim.x & 7) return (int)blockIdx.x;
  return (int)((blockIdx.x & 7) * (gridDim.x >> 3) + (blockIdx.x >> 3));
}

// ---------------------------------------------------------------------------
// bf16 MFMA GEMM: A [M][K] bf16, BT [N][K] bf16, 128x128 tile, BK=64.
// EPI 0: Cout(bf16)[m]=acc+bias ; 1: gelu ; 2: bf16 RMW window_reverse ;
// 3: bf16 RMW rowbase+m
template <int EPI>
__global__ __launch_bounds__(256) void k_gemm_mfma(const unsigned short* __restrict__ A,
                                                   const unsigned short* __restrict__ BT,
                                                   const float* __restrict__ bias,
                                                   void* __restrict__ Cout,
                                                   int rowbase, int N, int K, int nNt) {
  __shared__ __align__(128) unsigned short S[16384];   // 32 KB
  const int t = threadIdx.x;
  const int lane = t & 63, w = t >> 6;
  const int wr = w >> 1, wc = w & 1;
  const int lb = xcd_swz();
  const int n_t = lb % nNt, m_t = lb / nNt;
  const int m0 = m_t * BM, n0 = n_t * BN;
  const int l15 = lane & 15;
  const int sw = (lane & 7) << 3;
  const int rA = lane >> 3;
  const int kin = (((lane & 7) ^ rA) << 3);
  ffrag4 acc[4][4] = {};

  for (int k0 = 0; k0 < K; k0 += BK) {
#pragma unroll
    for (int i = 0; i < 4; ++i) {
      const int seg = i * 4 + w;
      const int row = seg * 8 + rA;
      gload16(A + (size_t)(m0 + row) * K + k0 + kin, (char*)S + seg * 1024);
      gload16(BT + (size_t)(n0 + row) * K + k0 + kin, (char*)S + 16384 + seg * 1024);
    }
    __syncthreads();
#pragma unroll
    for (int kk = 0; kk < BK; kk += 32) {
      bfrag8 af[4], bfr[4];
      const int colA = (kk + (lane >> 4) * 8) ^ sw;
#pragma unroll
      for (int mi = 0; mi < 4; ++mi) {
        int row = wr * 64 + mi * 16 + l15;
        af[mi] = *(const bfrag8*)&S[row * BK + colA];
      }
#pragma unroll
      for (int ni = 0; ni < 4; ++ni) {
        int col = wc * 64 + ni * 16 + l15;
        bfr[ni] = *(const bfrag8*)&S[8192 + col * BK + colA];
      }
#pragma unroll
      for (int mi = 0; mi < 4; ++mi)
#pragma unroll
        for (int ni = 0; ni < 4; ++ni)
          acc[mi][ni] = __builtin_amdgcn_mfma_f32_16x16x32_bf16(af[mi], bfr[ni], acc[mi][ni], 0, 0, 0);
    }
    __syncthreads();
  }

  const int cr = (lane >> 4) * 4;
  const int cc = l15;
  float bv[4];
#pragma unroll
  for (int ni = 0; ni < 4; ++ni) bv[ni] = bias[n0 + wc * 64 + ni * 16 + cc];

  float* Sf = (float*)S;    // 8192 f32 = 64 rows x 128 cols
#pragma unroll
  for (int pass = 0; pass < 2; ++pass) {
    if (wr == pass) {
#pragma unroll
      for (int mi = 0; mi < 4; ++mi) {
#pragma unroll
        for (int j = 0; j < 4; ++j) {
          const int mloc = mi * 16 + cr + j;
#pragma unroll
          for (int ni = 0; ni < 4; ++ni) {
            const int nl = wc * 64 + ni * 16 + cc;
            float v = acc[mi][ni][j] + bv[ni];
            if (EPI == 1) v = gelu_fast(v);
            Sf[mloc * 128 + nl] = v;
          }
        }
      }
    }
    __syncthreads();
#pragma unroll
    for (int r = 0; r < 4; ++r) {
      const int flat = (r * 256 + t) * 8;
      const int ml = flat >> 7, nl = flat & 127;
      float4 a = *(const float4*)&Sf[flat];
      float4 b2 = *(const float4*)&Sf[flat + 4];
      uint4 o;
      if (EPI == 2 || EPI == 3) {
        const int gm = rowbase + m0 + pass * 64 + ml;
        const int row = (EPI == 2) ? window_reverse_row(gm) : gm;
        unsigned short* dst = (unsigned short*)Cout + (size_t)row * N + n0 + nl;
        uint4 old = *(const uint4*)dst;
        o.x = cvtpk(bflo(old.x) + a.x, bfhi(old.x) + a.y);
        o.y = cvtpk(bflo(old.y) + a.z, bfhi(old.y) + a.w);
        o.z = cvtpk(bflo(old.z) + b2.x, bfhi(old.z) + b2.y);
        o.w = cvtpk(bflo(old.w) + b2.z, bfhi(old.w) + b2.w);
        *(uint4*)dst = o;
      } else {
        o.x = cvtpk(a.x, a.y);  o.y = cvtpk(a.z, a.w);
        o.z = cvtpk(b2.x, b2.y); o.w = cvtpk(b2.z, b2.w);
        *(uint4*)((unsigned short*)Cout + (size_t)(m0 + pass * 64 + ml) * N + n0 + nl) = o;
      }
    }
    if (pass == 0) __syncthreads();
  }
}

// ---------------------------------------------------------------------------
// FUSED MLP (64 KB LDS, 2 blocks/CU): tok += gelu(A @ fc1T + b1) @ fc2T + b2
// Block = 128 rows. LDS: Sstage 32K (A+fc1T k-step halves / fc2T col-half),
// Cl 32K bf16 h1-chunk [128][128] (granule-XOR, key=row&7). acc2[4][8] (128
// f32) + acch[4][4] (64 f32) in regs; launch_bounds(256,2) targets <=256 VGPR.
__global__ __launch_bounds__(256, 2) void k_mlp(const unsigned short* __restrict__ A,
                                                const unsigned short* __restrict__ fc1T,
                                                const unsigned short* __restrict__ fc2T,
                                                const float* __restrict__ b1g,
                                                const float* __restrict__ b2g,
                                                unsigned short* __restrict__ tok,
                                                int rowbase) {
  __shared__ __align__(128) char S[65536];
  unsigned short* Ss = (unsigned short*)S;              // 32 KB staging
  unsigned short* Cl = (unsigned short*)(S + 32768);    // 32 KB: [128][128]

  const int t = threadIdx.x;
  const int lane = t & 63, w = t >> 6;
  const int wr = w >> 1, wc = w & 1;
  const int l15 = lane & 15, g = lane >> 4;
  const int sw = (lane & 7) << 3;
  const int rA = lane >> 3;
  const int kin = (((lane & 7) ^ rA) << 3);
  const int cr = (lane >> 4) * 4, cc = l15;
  const int m0 = xcd_swz() * 128;

  ffrag4 acc2[4][8] = {};

  for (int hc = 0; hc < 8; ++hc) {
    float b1[4];
#pragma unroll
    for (int ni = 0; ni < 4; ++ni)
      b1[ni] = b1g[hc * 128 + wc * 64 + ni * 16 + cc];

    // ---- fc1 chunk: acch = A[128][256] @ fc1T[hc*128..+128][256]^T
    ffrag4 acch[4][4] = {};
    for (int k0 = 0; k0 < 256; k0 += 64) {
#pragma unroll
      for (int i = 0; i < 4; ++i) {
        const int seg = i * 4 + w;                // 0..15
        const int row = seg * 8 + rA;             // 0..127
        gload16(A + (size_t)(m0 + row) * 256 + k0 + kin, (char*)S + seg * 1024);
        gload16(fc1T + (size_t)(hc * 128 + row) * 256 + k0 + kin,
                (char*)S + 16384 + seg * 1024);
      }
      __syncthreads();
#pragma unroll
      for (int kk = 0; kk < 64; kk += 32) {
        bfrag8 af[4], bf[4];
        const int colA = (kk + g * 8) ^ sw;
#pragma unroll
        for (int mi = 0; mi < 4; ++mi)
          af[mi] = *(const bfrag8*)&Ss[(wr * 64 + mi * 16 + l15) * 64 + colA];
#pragma unroll
        for (int ni = 0; ni < 4; ++ni)
          bf[ni] = *(const bfrag8*)&Ss[8192 + (wc * 64 + ni * 16 + l15) * 64 + colA];
#pragma unroll
        for (int mi = 0; mi < 4; ++mi)
#pragma unroll
          for (int ni = 0; ni < 4; ++ni)
            acch[mi][ni] = __builtin_amdgcn_mfma_f32_16x16x32_bf16(af[mi], bf[ni], acch[mi][ni], 0, 0, 0);
      }
      __syncthreads();
    }

    // ---- gelu + bias -> Cl (bf16, granule-XOR key=row&7)
#pragma unroll
    for (int mi = 0; mi < 4; ++mi) {
#pragma unroll
      for (int j = 0; j < 4; ++j) {
        const int row = wr * 64 + mi * 16 + cr + j;
        const int k8 = (row & 7) << 3;
#pragma unroll
        for (int ni = 0; ni < 4; ++ni) {
          const int col = wc * 64 + ni * 16 + cc;
          Cl[row * 128 + (col ^ k8)] = f2bf(gelu_fast(acch[mi][ni][j] + b1[ni]));
        }
      }
    }

    // ---- out-gemm: acc2 += Cl[128][128] @ fc2T[256][hc*128..+128]^T (2 halves)
#pragma unroll
    for (int h = 0; h < 2; ++h) {
      // stage fc2T rows [0,256) x cols [hc*128+h*64, +64)  ([256][64])
#pragma unroll
      for (int i = 0; i < 8; ++i) {
        const int inst = i * 4 + w;               // 0..31
        const int r = inst * 8 + (lane >> 3);     // 0..255
        const int sg = hc * 128 + h * 64 + (((lane & 7) ^ (r & 7)) << 3);
        gload16(fc2T + (size_t)r * 1024 + sg, (char*)S + inst * 1024);
      }
      __syncthreads();   // stage done + (h==0) Cl writes visible
#pragma unroll
      for (int kk2 = 0; kk2 < 64; kk2 += 32) {
        bfrag8 af2[4], bf2[8];
        const int qC = ((h * 8 + (kk2 >> 3) + g) ^ (lane & 7)) << 3;
        const int qB = (((kk2 >> 3) + g) ^ (lane & 7)) << 3;
#pragma unroll
        for (int mi = 0; mi < 4; ++mi)
          af2[mi] = *(const bfrag8*)&Cl[(wr * 64 + mi * 16 + l15) * 128 + qC];
#pragma unroll
        for (int ni = 0; ni < 8; ++ni)
          bf2[ni] = *(const bfrag8*)&Ss[(wc * 128 + ni * 16 + l15) * 64 + qB];
#pragma unroll
        for (int mi = 0; mi < 4; ++mi)
#pragma unroll
          for (int ni = 0; ni < 8; ++ni)
            acc2[mi][ni] = __builtin_amdgcn_mfma_f32_16x16x32_bf16(af2[mi], bf2[ni], acc2[mi][ni], 0, 0, 0);
      }
      __syncthreads();   // reads done before next stage/Cl overwrite
    }
  }

  // ---- epilogue: tok[rowbase+m] += acc2 + b2  (f32 bounce, full 64 KB)
  float b2v[8];
#pragma unroll
  for (int ni = 0; ni < 8; ++ni) b2v[ni] = b2g[wc * 128 + ni * 16 + cc];

  float* Sf = (float*)S;    // 16384 f32 = 64 rows x 256 cols
#pragma unroll
  for (int pass = 0; pass < 2; ++pass) {
    if (wr == pass) {
#pragma unroll
      for (int mi = 0; mi < 4; ++mi) {
#pragma unroll
        for (int j = 0; j < 4; ++j) {
          const int mloc = mi * 16 + cr + j;
#pragma unroll
          for (int ni = 0; ni < 8; ++ni) {
            const int nl = wc * 128 + ni * 16 + cc;
            Sf[mloc * 256 + nl] = acc2[mi][ni][j] + b2v[ni];
          }
        }
      }
    }
    __syncthreads();
#pragma unroll
    for (int r = 0; r < 8; ++r) {
      const int flat = (r * 256 + t) * 8;
      const int ml = flat >> 8, nl = flat & 255;
      float4 a = *(const float4*)&Sf[flat];
      float4 b = *(const float4*)&Sf[flat + 4];
      const int gm = rowbase + m0 + pass * 64 + ml;
      unsigned short* dst = tok + (size_t)gm * 256 + nl;
      uint4 old = *(const uint4*)dst;
      uint4 o;
      o.x = cvtpk(bflo(old.x) + a.x, bfhi(old.x) + a.y);
      o.y = cvtpk(bflo(old.y) + a.z, bfhi(old.y) + a.w);
      o.z = cvtpk(bflo(old.z) + b.x, bfhi(old.z) + b.y);
      o.w = cvtpk(bflo(old.w) + b.z, bfhi(old.w) + b.w);
      *(uint4*)dst = o;
    }
    if (pass == 0) __syncthreads();
  }
}

// ---------------------------------------------------------------------------
__global__ __launch_bounds__(256) void k_wtrans(const float* __restrict__ w,
                                                unsigned short* __restrict__ wt,
                                                int K, int N) {
  __shared__ float tile[32][33];
  int k0 = blockIdx.x * 32, n0 = blockIdx.y * 32;
  int tx = threadIdx.x & 31, ty = threadIdx.x >> 5;
#pragma unroll
  for (int r = 0; r < 4; ++r)
    tile[ty + r * 8][tx] = w[(size_t)(k0 + ty + r * 8) * N + n0 + tx];
  __syncthreads();
#pragma unroll
  for (int r = 0; r < 4; ++r)
    wt[(size_t)(n0 + ty + r * 8) * K + k0 + tx] = f2bf(tile[tx][ty + r * 8]);
}

__global__ __launch_bounds__(256) void k_cast(const float* __restrict__ w,
                                              unsigned short* __restrict__ wb, int n) {
  int i = blockIdx.x * 256 + threadIdx.x;
  if (i < n) wb[i] = f2bf(w[i]);
}

__global__ __launch_bounds__(256) void k_transpose_x(const float* __restrict__ x,
                                                     unsigned short* __restrict__ xt) {
  __shared__ float tile[32][33];
  int b = blockIdx.x;
  int hw0 = blockIdx.y * 32;
  int c0 = blockIdx.z * 32;
  int tx = threadIdx.x & 31, ty = threadIdx.x >> 5;
#pragma unroll
  for (int r = 0; r < 4; ++r) {
    int c = c0 + ty + r * 8, hw = hw0 + tx;
    if (hw < HWTOK) tile[ty + r * 8][tx] = x[((size_t)b * 256 + c) * HWTOK + hw];
  }
  __syncthreads();
#pragma unroll
  for (int r = 0; r < 4; ++r) {
    int hw = hw0 + ty + r * 8, c = c0 + tx;
    if (hw < HWTOK) xt[((size_t)b * HWTOK + hw) * 256 + c] = f2bf(tile[tx][ty + r * 8]);
  }
}

// ---------------------------------------------------------------------------
template <bool WINDOW>
__global__ __launch_bounds__(256) void k_layernorm(const unsigned short* __restrict__ in,
                                                   const float* __restrict__ g,
                                                   const float* __restrict__ bta,
                                                   unsigned short* __restrict__ out,
                                                   int rowbase) {
  int wid = threadIdx.x >> 6, lane = threadIdx.x & 63;
  int li = blockIdx.x * 4 + wid;
  int token = rowbase + li;
  const uint2 xr = *(const uint2*)(in + (size_t)token * 256 + lane * 4);
  float x0 = bflo(xr.x), x1 = bfhi(xr.x), x2 = bflo(xr.y), x3 = bfhi(xr.y);
  float s = x0 + x1 + x2 + x3;
  float sq = x0 * x0 + x1 * x1 + x2 * x2 + x3 * x3;
#pragma unroll
  for (int off = 32; off >= 1; off >>= 1) {
    s += __shfl_xor(s, off);
    sq += __shfl_xor(sq, off);
  }
  float mean = s * (1.f / 256.f);
  float var = sq * (1.f / 256.f) - mean * mean;
  float rstd = rsqrtf(var + 1e-5f);
  float4 gv = *(const float4*)(g + lane * 4);
  float4 bv = *(const float4*)(bta + lane * 4);
  uint2 ov;
  ov.x = cvtpk((x0 - mean) * rstd * gv.x + bv.x,
               (x1 - mean) * rstd * gv.y + bv.y);
  ov.y = cvtpk((x2 - mean) * rstd * gv.z + bv.z,
               (x3 - mean) * rstd * gv.w + bv.w);
  int orow;
  if (WINDOW) {
    int b = token / 196, hw = token % 196;
    int h14 = hw / 14, w14 = hw % 14;
    int wh = h14 / 7, i = h14 % 7, ww = w14 / 7, j = w14 % 7;
    int widx = (b * 2 + wh) * 2 + ww;
    orow = widx * 49 + i * 7 + j - rowbase;
  } else {
    orow = li;
  }
  *(uint2*)(out + (size_t)orow * 256 + lane * 4) = ov;
}

// ---------------------------------------------------------------------------
__global__ __launch_bounds__(256) void k_attention(const unsigned short* __restrict__ qkv,
                                                   const float* __restrict__ rpb,
                                                   unsigned short* __restrict__ o) {
  __shared__ unsigned short Kl[4][64 * 40];
  __shared__ unsigned short VTl[4][32 * 72];
  __shared__ unsigned short Pl[4][64 * 72];
  __shared__ float rpbl[4][176];

  const int t = threadIdx.x;
  const int w4 = t >> 6, lane = t & 63;
  const int l15 = lane & 15, g = lane >> 4;
  const int gw = blockIdx.x * 4 + w4;
  const int lw = gw >> 3, head = gw & 7;

  unsigned short* K_ = Kl[w4];
  unsigned short* VT_ = VTl[w4];
  unsigned short* P_ = Pl[w4];
  float* rpb_ = rpbl[w4];

  const size_t baseq = (size_t)lw * 49 * 768 + head * 32;

  for (int e = lane; e < 169; e += 64) rpb_[e] = rpb[e * 8 + head];

  for (int e = lane; e < 512; e += 64) {
    int d = e >> 4, tk = 48 + (e & 15);
    if ((e & 15) != 0) VT_[d * 72 + tk] = 0;
  }

  for (int e = lane; e < 784; e += 64) {
    int tok = e >> 4, dp = e & 15;
    unsigned kv = *(const unsigned*)(qkv + baseq + 256 + (size_t)tok * 768 + dp * 2);
    *(unsigned*)&K_[tok * 40 + dp * 2] = kv;
    unsigned vv = *(const unsigned*)(qkv + baseq + 512 + (size_t)tok * 768 + dp * 2);
    VT_[(dp * 2 + 0) * 72 + tok] = (unsigned short)(vv & 0xffffu);
    VT_[(dp * 2 + 1) * 72 + tok] = (unsigned short)(vv >> 16);
  }

  ffrag4 acc[4][4] = {};
  {
    bfrag8 af[4], bfr[4];
#pragma unroll
    for (int qi = 0; qi < 4; ++qi)
      af[qi] = *(const bfrag8*)(qkv + baseq + (size_t)(16 * qi + l15) * 768 + g * 8);
#pragma unroll
    for (int kj = 0; kj < 4; ++kj)
      bfr[kj] = *(const bfrag8*)&K_[(16 * kj + l15) * 40 + g * 8];
#pragma unroll
    for (int qi = 0; qi < 4; ++qi)
#pragma unroll
      for (int kj = 0; kj < 4; ++kj)
        acc[qi][kj] = __builtin_amdgcn_mfma_f32_16x16x32_bf16(af[qi], bfr[kj], acc[qi][kj], 0, 0, 0);
  }

  const float scale = 0.17677669529663687f;
  int kc[4];
  bool kvalid[4];
#pragma unroll
  for (int kj = 0; kj < 4; ++kj) {
    int c = 16 * kj + l15;
    kc[kj] = 13 * (c / 7) + (c % 7);
    kvalid[kj] = (c < 49);
  }
#pragma unroll
  for (int qi = 0; qi < 4; ++qi) {
#pragma unroll
    for (int j = 0; j < 4; ++j) {
      int q = 16 * qi + 4 * g + j;
      int qc = 13 * (q / 7) + (q % 7);
      float tv[4];
#pragma unroll
      for (int kj = 0; kj < 4; ++kj)
        tv[kj] = kvalid[kj] ? (acc[qi][kj][j] * scale + rpb_[qc - kc[kj] + 84]) : -INFINITY;
      float mx = fmaxf(fmaxf(tv[0], tv[1]), fmaxf(tv[2], tv[3]));
#pragma unroll
      for (int off = 8; off >= 1; off >>= 1) mx = fmaxf(mx, __shfl_xor(mx, off));
      float p[4], sum = 0.f;
#pragma unroll
      for (int kj = 0; kj < 4; ++kj) {
        p[kj] = kvalid[kj] ? __expf(tv[kj] - mx) : 0.f;
        sum += p[kj];
      }
#pragma unroll
      for (int off = 8; off >= 1; off >>= 1) sum += __shfl_xor(sum, off);
      float inv = __builtin_amdgcn_rcpf(sum);
      if (q < 49) {
#pragma unroll
        for (int kj = 0; kj < 4; ++kj)
          P_[q * 72 + 16 * kj + l15] = f2bf(p[kj] * inv);
      }
    }
  }

  ffrag4 accO[2][4] = {};
#pragma unroll
  for (int kk = 0; kk < 64; kk += 32) {
    bfrag8 af2[2], bf2[4];
#pragma unroll
    for (int ti = 0; ti < 2; ++ti)
      af2[ti] = *(const bfrag8*)&VT_[(16 * ti + l15) * 72 + kk + g * 8];
#pragma unroll
    for (int qj = 0; qj < 4; ++qj)
      bf2[qj] = *(const bfrag8*)&P_[(16 * qj + l15) * 72 + kk + g * 8];
#pragma unroll
    for (int ti = 0; ti < 2; ++ti)
#pragma unroll
      for (int qj = 0; qj < 4; ++qj)
        accO[ti][qj] = __builtin_amdgcn_mfma_f32_16x16x32_bf16(af2[ti], bf2[qj], accO[ti][qj], 0, 0, 0);
  }

#pragma unroll
  for (int qj = 0; qj < 4; ++qj) {
    int q = 16 * qj + l15;
    if (q < 49) {
#pragma unroll
      for (int ti = 0; ti < 2; ++ti) {
        uint2 ov;
        ov.x = cvtpk(accO[ti][qj][0], accO[ti][qj][1]);
        ov.y = cvtpk(accO[ti][qj][2], accO[ti][qj][3]);
        *(uint2*)(o + ((size_t)lw * 49 + q) * 256 + head * 32 + 16 * ti + 4 * g) = ov;
      }
    }
  }
}

// ---------------------------------------------------------------------------
__global__ __launch_bounds__(256) void k_pool(const unsigned short* __restrict__ tok,
                                              float* __restrict__ pooled) {
  int b = blockIdx.x, c = threadIdx.x;
  float s = 0.f;
  for (int hw = 0; hw < 196; ++hw) s += bf2f(tok[((size_t)b * 196 + hw) * 256 + c]);
  pooled[b * 256 + c] = s * (1.f / 196.f);
}

__global__ __launch_bounds__(64) void k_head(const float* __restrict__ pooled,
                                             const float* __restrict__ w,
                                             const float* __restrict__ bias,
                                             float* __restrict__ out) {
  int b = blockIdx.x, t = threadIdx.x;
  if (t < 7) {
    float s = bias[t];
    for (int c = 0; c < 256; ++c) s = fmaf(pooled[b * 256 + c], w[c * 7 + t], s);
    out[b * 7 + t] = s;
  }
}

// ---------------------------------------------------------------------------
extern "C" void kernel_launch(void* const* d_in, const int* in_sizes, int n_in,
                              void* d_out, int out_size, void* d_ws, size_t ws_size,
                              hipStream_t stream) {
  const float* x      = (const float*)d_in[0];
  const float* conv_w = (const float*)d_in[1];
  const float* conv_b = (const float*)d_in[2];
  const float* ln1_g  = (const float*)d_in[3];
  const float* ln1_b  = (const float*)d_in[4];
  const float* qkv_w  = (const float*)d_in[5];
  const float* qkv_b  = (const float*)d_in[6];
  const float* rpb    = (const float*)d_in[7];
  const float* proj_w = (const float*)d_in[8];
  const float* proj_b = (const float*)d_in[9];
  const float* ln2_g  = (const float*)d_in[10];
  const float* ln2_b  = (const float*)d_in[11];
  const float* fc1_w  = (const float*)d_in[12];
  const float* fc1_b  = (const float*)d_in[13];
  const float* fc2_w  = (const float*)d_in[14];
  const float* fc2_b  = (const float*)d_in[15];
  const float* fco_w  = (const float*)d_in[16];
  const float* fco_b  = (const float*)d_in[17];
  float* out = (float*)d_out;
  char* p = (char*)d_ws;

  const size_t FULL_NEED = 182000000ull;
  const int nch = (ws_size >= FULL_NEED) ? 1 : 4;
  const int chw = 1024 / nch;
  const size_t chrows = (size_t)chw * 49;
  const int nMt = (int)(chrows / BM);

  unsigned short* tok = (unsigned short*)p;   p += (size_t)MTOT * 256 * 2;
  unsigned short* Bbuf = (unsigned short*)p;  p += chrows * 1024 * 2;
  unsigned short* Abuf = (unsigned short*)p;  p += chrows * 256 * 2;
  unsigned short* Cbuf = (unsigned short*)p;  p += chrows * 256 * 2;
  unsigned short* cwB  = (unsigned short*)p;  p += 65536 * 2;
  unsigned short* qkvT = (unsigned short*)p;  p += 196608 * 2;
  unsigned short* projT= (unsigned short*)p;  p += 65536 * 2;
  unsigned short* fc1T = (unsigned short*)p;  p += 262144 * 2;
  unsigned short* fc2T = (unsigned short*)p;  p += 262144 * 2;
  float* pool = (float*)p;                    p += 65536 * 4;
  unsigned short* xt = Bbuf;

  k_cast<<<256, 256, 0, stream>>>(conv_w, cwB, 65536);
  k_wtrans<<<dim3(8, 24), 256, 0, stream>>>(qkv_w, qkvT, 256, 768);
  k_wtrans<<<dim3(8, 8), 256, 0, stream>>>(proj_w, projT, 256, 256);
  k_wtrans<<<dim3(8, 32), 256, 0, stream>>>(fc1_w, fc1T, 256, 1024);
  k_wtrans<<<dim3(32, 8), 256, 0, stream>>>(fc2_w, fc2T, 1024, 256);

  k_transpose_x<<<dim3(BATCH, 7, 8), 256, 0, stream>>>(x, xt);
  k_gemm_mfma<0><<<(MTOT / BM) * 2, 256, 0, stream>>>(xt, cwB, conv_b, tok, 0, 256, 256, 2);

  for (int c = 0; c < nch; ++c) {
    const int rowbase = c * (int)chrows;
    k_layernorm<true><<<chrows / 4, 256, 0, stream>>>(tok, ln1_g, ln1_b, Abuf, rowbase);
    k_gemm_mfma<0><<<nMt * 6, 256, 0, stream>>>(Abuf, qkvT, qkv_b, Bbuf, 0, 768, 256, 6);
    k_attention<<<chw * 2, 256, 0, stream>>>(Bbuf, rpb, Cbuf);
    k_gemm_mfma<2><<<nMt * 2, 256, 0, stream>>>(Cbuf, projT, proj_b, tok, rowbase, 256, 256, 2);
    k_layernorm<false><<<chrows / 4, 256, 0, stream>>>(tok, ln2_g, ln2_b, Abuf, rowbase);
    // fused MLP: tok += gelu(Abuf @ fc1T + b1) @ fc2T + b2
    k_mlp<<<nMt, 256, 0, stream>>>(Abuf, fc1T, fc2T, fc1_b, fc2_b, tok, rowbase);
  }

  k_pool<<<BATCH, 256, 0, stream>>>(tok, pool);
  k_head<<<BATCH, 64, 0, stream>>>(pool, fco_w, fco_b, out);
}

// Round 19
// 307.619 us; speedup vs baseline: 1.5231x; 1.5231x over previous
//
#include <hip/hip_runtime.h>
#include <math.h>

#define NHEADS 8
#define BATCH  256
#define HWTOK  196
#define MTOT   50176          // 1024 windows * 49

#define BM 128
#define BN 128
#define BK 64

typedef short bfrag8 __attribute__((ext_vector_type(8)));
typedef float ffrag4 __attribute__((ext_vector_type(4)));

// ---------------------------------------------------------------------------
__device__ __forceinline__ unsigned short f2bf(float f) {
  union { float f; unsigned u; } v; v.f = f;
  unsigned r = v.u + 0x7fffu + ((v.u >> 16) & 1u);   // RNE
  return (unsigned short)(r >> 16);
}
__device__ __forceinline__ float bf2f(unsigned short b) {
  union { unsigned u; float f; } v; v.u = ((unsigned)b) << 16;
  return v.f;
}
__device__ __forceinline__ float bflo(unsigned u) {
  union { unsigned x; float f; } v; v.x = u << 16; return v.f;
}
__device__ __forceinline__ float bfhi(unsigned u) {
  union { unsigned x; float f; } v; v.x = u & 0xffff0000u; return v.f;
}
// packed bf16 convert: lo = bf16(a), hi = bf16(b), RNE
__device__ __forceinline__ unsigned cvtpk(float a, float b) {
  unsigned r;
  asm("v_cvt_pk_bf16_f32 %0, %1, %2" : "=v"(r) : "v"(a), "v"(b));
  return r;
}
// GELU exact-erf (A&S 7.1.26, |err|<=1.5e-7) with fast rcp
__device__ __forceinline__ float gelu_fast(float x) {
  float ax = fabsf(x);
  float z = ax * 0.70710678118654752f;
  float t = __builtin_amdgcn_rcpf(fmaf(z, 0.3275911f, 1.0f));
  float y = t * (0.254829592f +
            t * (-0.284496736f +
            t * (1.421413741f +
            t * (-1.453152027f +
            t * 1.061405429f))));
  float e2 = __expf(-z * z);
  float erfv = fmaf(-y, e2, 1.0f);
  return 0.5f * fmaf(ax, erfv, x);
}
__device__ __forceinline__ int window_reverse_row(int m) {
  int widx = m / 49, pos = m % 49;
  int b = widx >> 2, wh = (widx >> 1) & 1, ww = widx & 1;
  int i = pos / 7, j = pos % 7;
  return b * 196 + (wh * 7 + i) * 14 + (ww * 7 + j);
}

__device__ __forceinline__ void gload16(const void* g, void* l) {
  __builtin_amdgcn_global_load_lds(
      (const __attribute__((address_space(1))) void*)g,
      (__attribute__((address_space(3))) void*)l, 16, 0, 0);
}

// ---------------------------------------------------------------------------
// bf16 MFMA GEMM: A [M][K] bf16, BT [N][K] bf16, 128x128 tile, BK=64.
// Single-buffered m97 2-barrier K-loop, XOR-swizzled LDS, XCD-chunked block
// swizzle + n-fastest tile order, f32-LDS-bounce epilogues + cvt_pk packing.
// EPI 0: Cout(bf16)[m] = acc+bias
// EPI 1: Cout(bf16)[m] = gelu(acc+bias)
// EPI 2: Cout(bf16)[wrr(rowbase+m)] += acc+bias   (residual RMW, bf16)
// EPI 3: Cout(bf16)[rowbase+m]      += acc+bias   (residual RMW, bf16)
template <int EPI>
__global__ __launch_bounds__(256) void k_gemm_mfma(const unsigned short* __restrict__ A,
                                                   const unsigned short* __restrict__ BT,
                                                   const float* __restrict__ bias,
                                                   void* __restrict__ Cout,
                                                   int rowbase, int N, int K, int nNt) {
  __shared__ __align__(128) unsigned short S[16384];   // 32 KB
  const int t = threadIdx.x;
  const int lane = t & 63, w = t >> 6;
  const int wr = w >> 1, wc = w & 1;
  const int cpx = gridDim.x >> 3;
  const int lb = (blockIdx.x & 7) * cpx + (blockIdx.x >> 3);
  const int n_t = lb % nNt, m_t = lb / nNt;
  const int m0 = m_t * BM, n0 = n_t * BN;
  const int l15 = lane & 15;
  const int sw = (lane & 7) << 3;                 // read-side XOR (elements)
  const int rA = lane >> 3;                       // staging row within segment
  const int kin = (((lane & 7) ^ rA) << 3);       // swizzled source col (elems)
  ffrag4 acc[4][4] = {};

  for (int k0 = 0; k0 < K; k0 += BK) {
#pragma unroll
    for (int i = 0; i < 4; ++i) {
      const int seg = i * 4 + w;                  // wave-uniform 0..15
      const int row = seg * 8 + rA;               // 0..127
      gload16(A + (size_t)(m0 + row) * K + k0 + kin, (char*)S + seg * 1024);
      gload16(BT + (size_t)(n0 + row) * K + k0 + kin, (char*)S + 16384 + seg * 1024);
    }
    __syncthreads();
#pragma unroll
    for (int kk = 0; kk < BK; kk += 32) {
      bfrag8 af[4], bfr[4];
      const int colA = (kk + (lane >> 4) * 8) ^ sw;
#pragma unroll
      for (int mi = 0; mi < 4; ++mi) {
        int row = wr * 64 + mi * 16 + l15;
        af[mi] = *(const bfrag8*)&S[row * BK + colA];
      }
#pragma unroll
      for (int ni = 0; ni < 4; ++ni) {
        int col = wc * 64 + ni * 16 + l15;
        bfr[ni] = *(const bfrag8*)&S[8192 + col * BK + colA];
      }
#pragma unroll
      for (int mi = 0; mi < 4; ++mi)
#pragma unroll
        for (int ni = 0; ni < 4; ++ni)
          acc[mi][ni] = __builtin_amdgcn_mfma_f32_16x16x32_bf16(af[mi], bfr[ni], acc[mi][ni], 0, 0, 0);
    }
    __syncthreads();
  }

  const int cr = (lane >> 4) * 4;
  const int cc = l15;
  float bv[4];
#pragma unroll
  for (int ni = 0; ni < 4; ++ni) bv[ni] = bias[n0 + wc * 64 + ni * 16 + cc];

  // f32 bounce, two half-tile passes (rows [pass*64, pass*64+64))
  float* Sf = (float*)S;    // 8192 f32 = 64 rows x 128 cols
#pragma unroll
  for (int pass = 0; pass < 2; ++pass) {
    if (wr == pass) {
#pragma unroll
      for (int mi = 0; mi < 4; ++mi) {
#pragma unroll
        for (int j = 0; j < 4; ++j) {
          const int mloc = mi * 16 + cr + j;      // 0..63
#pragma unroll
          for (int ni = 0; ni < 4; ++ni) {
            const int nl = wc * 64 + ni * 16 + cc;
            float v = acc[mi][ni][j] + bv[ni];
            if (EPI == 1) v = gelu_fast(v);
            Sf[mloc * 128 + nl] = v;
          }
        }
      }
    }
    __syncthreads();
#pragma unroll
    for (int r = 0; r < 4; ++r) {
      const int flat = (r * 256 + t) * 8;         // f32 index, 0..8191
      const int ml = flat >> 7, nl = flat & 127;
      float4 a = *(const float4*)&Sf[flat];
      float4 b2 = *(const float4*)&Sf[flat + 4];
      uint4 o;
      if (EPI == 2 || EPI == 3) {
        const int gm = rowbase + m0 + pass * 64 + ml;
        const int row = (EPI == 2) ? window_reverse_row(gm) : gm;
        unsigned short* dst = (unsigned short*)Cout + (size_t)row * N + n0 + nl;
        uint4 old = *(const uint4*)dst;
        o.x = cvtpk(bflo(old.x) + a.x, bfhi(old.x) + a.y);
        o.y = cvtpk(bflo(old.y) + a.z, bfhi(old.y) + a.w);
        o.z = cvtpk(bflo(old.z) + b2.x, bfhi(old.z) + b2.y);
        o.w = cvtpk(bflo(old.w) + b2.z, bfhi(old.w) + b2.w);
        *(uint4*)dst = o;
      } else {
        o.x = cvtpk(a.x, a.y);  o.y = cvtpk(a.z, a.w);
        o.z = cvtpk(b2.x, b2.y); o.w = cvtpk(b2.z, b2.w);
        *(uint4*)((unsigned short*)Cout + (size_t)(m0 + pass * 64 + ml) * N + n0 + nl) = o;
      }
    }
    if (pass == 0) __syncthreads();
  }
}

// ---------------------------------------------------------------------------
__global__ __launch_bounds__(256) void k_wtrans(const float* __restrict__ w,
                                                unsigned short* __restrict__ wt,
                                                int K, int N) {
  __shared__ float tile[32][33];
  int k0 = blockIdx.x * 32, n0 = blockIdx.y * 32;
  int tx = threadIdx.x & 31, ty = threadIdx.x >> 5;
#pragma unroll
  for (int r = 0; r < 4; ++r)
    tile[ty + r * 8][tx] = w[(size_t)(k0 + ty + r * 8) * N + n0 + tx];
  __syncthreads();
#pragma unroll
  for (int r = 0; r < 4; ++r)
    wt[(size_t)(n0 + ty + r * 8) * K + k0 + tx] = f2bf(tile[tx][ty + r * 8]);
}

__global__ __launch_bounds__(256) void k_cast(const float* __restrict__ w,
                                              unsigned short* __restrict__ wb, int n) {
  int i = blockIdx.x * 256 + threadIdx.x;
  if (i < n) wb[i] = f2bf(w[i]);
}

__global__ __launch_bounds__(256) void k_transpose_x(const float* __restrict__ x,
                                                     unsigned short* __restrict__ xt) {
  __shared__ float tile[32][33];
  int b = blockIdx.x;
  int hw0 = blockIdx.y * 32;
  int c0 = blockIdx.z * 32;
  int tx = threadIdx.x & 31, ty = threadIdx.x >> 5;
#pragma unroll
  for (int r = 0; r < 4; ++r) {
    int c = c0 + ty + r * 8, hw = hw0 + tx;
    if (hw < HWTOK) tile[ty + r * 8][tx] = x[((size_t)b * 256 + c) * HWTOK + hw];
  }
  __syncthreads();
#pragma unroll
  for (int r = 0; r < 4; ++r) {
    int hw = hw0 + ty + r * 8, c = c0 + tx;
    if (hw < HWTOK) xt[((size_t)b * HWTOK + hw) * 256 + c] = f2bf(tile[tx][ty + r * 8]);
  }
}

// ---------------------------------------------------------------------------
// LayerNorm over C=256, one wave/token, bf16 in -> bf16 out (chunk-local rows).
template <bool WINDOW>
__global__ __launch_bounds__(256) void k_layernorm(const unsigned short* __restrict__ in,
                                                   const float* __restrict__ g,
                                                   const float* __restrict__ bta,
                                                   unsigned short* __restrict__ out,
                                                   int rowbase) {
  int wid = threadIdx.x >> 6, lane = threadIdx.x & 63;
  int li = blockIdx.x * 4 + wid;
  int token = rowbase + li;
  const uint2 xr = *(const uint2*)(in + (size_t)token * 256 + lane * 4);
  float x0 = bflo(xr.x), x1 = bfhi(xr.x), x2 = bflo(xr.y), x3 = bfhi(xr.y);
  float s = x0 + x1 + x2 + x3;
  float sq = x0 * x0 + x1 * x1 + x2 * x2 + x3 * x3;
#pragma unroll
  for (int off = 32; off >= 1; off >>= 1) {
    s += __shfl_xor(s, off);
    sq += __shfl_xor(sq, off);
  }
  float mean = s * (1.f / 256.f);
  float var = sq * (1.f / 256.f) - mean * mean;
  float rstd = rsqrtf(var + 1e-5f);
  float4 gv = *(const float4*)(g + lane * 4);
  float4 bv = *(const float4*)(bta + lane * 4);
  uint2 ov;
  ov.x = cvtpk((x0 - mean) * rstd * gv.x + bv.x,
               (x1 - mean) * rstd * gv.y + bv.y);
  ov.y = cvtpk((x2 - mean) * rstd * gv.z + bv.z,
               (x3 - mean) * rstd * gv.w + bv.w);
  int orow;
  if (WINDOW) {
    int b = token / 196, hw = token % 196;
    int h14 = hw / 14, w14 = hw % 14;
    int wh = h14 / 7, i = h14 % 7, ww = w14 / 7, j = w14 % 7;
    int widx = (b * 2 + wh) * 2 + ww;
    orow = widx * 49 + i * 7 + j - rowbase;
  } else {
    orow = li;
  }
  *(uint2*)(out + (size_t)orow * 256 + lane * 4) = ov;
}

// ---------------------------------------------------------------------------
// MFMA attention: one WAVE per (window, head); 4 independent waves per block.
__global__ __launch_bounds__(256) void k_attention(const unsigned short* __restrict__ qkv,
                                                   const float* __restrict__ rpb,
                                                   unsigned short* __restrict__ o) {
  __shared__ unsigned short Kl[4][64 * 40];
  __shared__ unsigned short VTl[4][32 * 72];
  __shared__ unsigned short Pl[4][64 * 72];
  __shared__ float rpbl[4][176];

  const int t = threadIdx.x;
  const int w4 = t >> 6, lane = t & 63;
  const int l15 = lane & 15, g = lane >> 4;
  const int gw = blockIdx.x * 4 + w4;
  const int lw = gw >> 3, head = gw & 7;

  unsigned short* K_ = Kl[w4];
  unsigned short* VT_ = VTl[w4];
  unsigned short* P_ = Pl[w4];
  float* rpb_ = rpbl[w4];

  const size_t baseq = (size_t)lw * 49 * 768 + head * 32;

  for (int e = lane; e < 169; e += 64) rpb_[e] = rpb[e * 8 + head];

  for (int e = lane; e < 512; e += 64) {
    int d = e >> 4, tk = 48 + (e & 15);
    if ((e & 15) != 0) VT_[d * 72 + tk] = 0;
  }

  for (int e = lane; e < 784; e += 64) {
    int tok = e >> 4, dp = e & 15;
    unsigned kv = *(const unsigned*)(qkv + baseq + 256 + (size_t)tok * 768 + dp * 2);
    *(unsigned*)&K_[tok * 40 + dp * 2] = kv;
    unsigned vv = *(const unsigned*)(qkv + baseq + 512 + (size_t)tok * 768 + dp * 2);
    VT_[(dp * 2 + 0) * 72 + tok] = (unsigned short)(vv & 0xffffu);
    VT_[(dp * 2 + 1) * 72 + tok] = (unsigned short)(vv >> 16);
  }

  ffrag4 acc[4][4] = {};
  {
    bfrag8 af[4], bfr[4];
#pragma unroll
    for (int qi = 0; qi < 4; ++qi)
      af[qi] = *(const bfrag8*)(qkv + baseq + (size_t)(16 * qi + l15) * 768 + g * 8);
#pragma unroll
    for (int kj = 0; kj < 4; ++kj)
      bfr[kj] = *(const bfrag8*)&K_[(16 * kj + l15) * 40 + g * 8];
#pragma unroll
    for (int qi = 0; qi < 4; ++qi)
#pragma unroll
      for (int kj = 0; kj < 4; ++kj)
        acc[qi][kj] = __builtin_amdgcn_mfma_f32_16x16x32_bf16(af[qi], bfr[kj], acc[qi][kj], 0, 0, 0);
  }

  const float scale = 0.17677669529663687f;
  int kc[4];
  bool kvalid[4];
#pragma unroll
  for (int kj = 0; kj < 4; ++kj) {
    int c = 16 * kj + l15;
    kc[kj] = 13 * (c / 7) + (c % 7);
    kvalid[kj] = (c < 49);
  }
#pragma unroll
  for (int qi = 0; qi < 4; ++qi) {
#pragma unroll
    for (int j = 0; j < 4; ++j) {
      int q = 16 * qi + 4 * g + j;
      int qc = 13 * (q / 7) + (q % 7);
      float tv[4];
#pragma unroll
      for (int kj = 0; kj < 4; ++kj)
        tv[kj] = kvalid[kj] ? (acc[qi][kj][j] * scale + rpb_[qc - kc[kj] + 84]) : -INFINITY;
      float mx = fmaxf(fmaxf(tv[0], tv[1]), fmaxf(tv[2], tv[3]));
#pragma unroll
      for (int off = 8; off >= 1; off >>= 1) mx = fmaxf(mx, __shfl_xor(mx, off));
      float p[4], sum = 0.f;
#pragma unroll
      for (int kj = 0; kj < 4; ++kj) {
        p[kj] = kvalid[kj] ? __expf(tv[kj] - mx) : 0.f;
        sum += p[kj];
      }
#pragma unroll
      for (int off = 8; off >= 1; off >>= 1) sum += __shfl_xor(sum, off);
      float inv = __builtin_amdgcn_rcpf(sum);
      if (q < 49) {
#pragma unroll
        for (int kj = 0; kj < 4; ++kj)
          P_[q * 72 + 16 * kj + l15] = f2bf(p[kj] * inv);
      }
    }
  }

  ffrag4 accO[2][4] = {};
#pragma unroll
  for (int kk = 0; kk < 64; kk += 32) {
    bfrag8 af2[2], bf2[4];
#pragma unroll
    for (int ti = 0; ti < 2; ++ti)
      af2[ti] = *(const bfrag8*)&VT_[(16 * ti + l15) * 72 + kk + g * 8];
#pragma unroll
    for (int qj = 0; qj < 4; ++qj)
      bf2[qj] = *(const bfrag8*)&P_[(16 * qj + l15) * 72 + kk + g * 8];
#pragma unroll
    for (int ti = 0; ti < 2; ++ti)
#pragma unroll
      for (int qj = 0; qj < 4; ++qj)
        accO[ti][qj] = __builtin_amdgcn_mfma_f32_16x16x32_bf16(af2[ti], bf2[qj], accO[ti][qj], 0, 0, 0);
  }

#pragma unroll
  for (int qj = 0; qj < 4; ++qj) {
    int q = 16 * qj + l15;
    if (q < 49) {
#pragma unroll
      for (int ti = 0; ti < 2; ++ti) {
        uint2 ov;
        ov.x = cvtpk(accO[ti][qj][0], accO[ti][qj][1]);
        ov.y = cvtpk(accO[ti][qj][2], accO[ti][qj][3]);
        *(uint2*)(o + ((size_t)lw * 49 + q) * 256 + head * 32 + 16 * ti + 4 * g) = ov;
      }
    }
  }
}

// ---------------------------------------------------------------------------
__global__ __launch_bounds__(256) void k_pool(const unsigned short* __restrict__ tok,
                                              float* __restrict__ pooled) {
  int b = blockIdx.x, c = threadIdx.x;
  float s = 0.f;
  for (int hw = 0; hw < 196; ++hw) s += bf2f(tok[((size_t)b * 196 + hw) * 256 + c]);
  pooled[b * 256 + c] = s * (1.f / 196.f);
}

__global__ __launch_bounds__(64) void k_head(const float* __restrict__ pooled,
                                             const float* __restrict__ w,
                                             const float* __restrict__ bias,
                                             float* __restrict__ out) {
  int b = blockIdx.x, t = threadIdx.x;
  if (t < 7) {
    float s = bias[t];
    for (int c = 0; c < 256; ++c) s = fmaf(pooled[b * 256 + c], w[c * 7 + t], s);
    out[b * 7 + t] = s;
  }
}

// ---------------------------------------------------------------------------
extern "C" void kernel_launch(void* const* d_in, const int* in_sizes, int n_in,
                              void* d_out, int out_size, void* d_ws, size_t ws_size,
                              hipStream_t stream) {
  const float* x      = (const float*)d_in[0];
  const float* conv_w = (const float*)d_in[1];
  const float* conv_b = (const float*)d_in[2];
  const float* ln1_g  = (const float*)d_in[3];
  const float* ln1_b  = (const float*)d_in[4];
  const float* qkv_w  = (const float*)d_in[5];
  const float* qkv_b  = (const float*)d_in[6];
  const float* rpb    = (const float*)d_in[7];
  const float* proj_w = (const float*)d_in[8];
  const float* proj_b = (const float*)d_in[9];
  const float* ln2_g  = (const float*)d_in[10];
  const float* ln2_b  = (const float*)d_in[11];
  const float* fc1_w  = (const float*)d_in[12];
  const float* fc1_b  = (const float*)d_in[13];
  const float* fc2_w  = (const float*)d_in[14];
  const float* fc2_b  = (const float*)d_in[15];
  const float* fco_w  = (const float*)d_in[16];
  const float* fco_b  = (const float*)d_in[17];
  float* out = (float*)d_out;
  char* p = (char*)d_ws;

  // bf16 tok: full-M needs ~182 MB; chunked (4 chunks) ~66 MB fallback.
  const size_t FULL_NEED = 182000000ull;
  const int nch = (ws_size >= FULL_NEED) ? 1 : 4;
  const int chw = 1024 / nch;
  const size_t chrows = (size_t)chw * 49;
  const int nMt = (int)(chrows / BM);

  unsigned short* tok = (unsigned short*)p;   p += (size_t)MTOT * 256 * 2;
  unsigned short* Bbuf = (unsigned short*)p;  p += chrows * 1024 * 2;
  unsigned short* Abuf = (unsigned short*)p;  p += chrows * 256 * 2;
  unsigned short* Cbuf = (unsigned short*)p;  p += chrows * 256 * 2;
  unsigned short* cwB  = (unsigned short*)p;  p += 65536 * 2;
  unsigned short* qkvT = (unsigned short*)p;  p += 196608 * 2;
  unsigned short* projT= (unsigned short*)p;  p += 65536 * 2;
  unsigned short* fc1T = (unsigned short*)p;  p += 262144 * 2;
  unsigned short* fc2T = (unsigned short*)p;  p += 262144 * 2;
  float* pool = (float*)p;                    p += 65536 * 4;
  unsigned short* xt = Bbuf;

  k_cast<<<256, 256, 0, stream>>>(conv_w, cwB, 65536);
  k_wtrans<<<dim3(8, 24), 256, 0, stream>>>(qkv_w, qkvT, 256, 768);
  k_wtrans<<<dim3(8, 8), 256, 0, stream>>>(proj_w, projT, 256, 256);
  k_wtrans<<<dim3(8, 32), 256, 0, stream>>>(fc1_w, fc1T, 256, 1024);
  k_wtrans<<<dim3(32, 8), 256, 0, stream>>>(fc2_w, fc2T, 1024, 256);

  k_transpose_x<<<dim3(BATCH, 7, 8), 256, 0, stream>>>(x, xt);
  // conv -> tok (bf16, token-major)
  k_gemm_mfma<0><<<(MTOT / BM) * 2, 256, 0, stream>>>(xt, cwB, conv_b, tok, 0, 256, 256, 2);

  for (int c = 0; c < nch; ++c) {
    const int rowbase = c * (int)chrows;
    k_layernorm<true><<<chrows / 4, 256, 0, stream>>>(tok, ln1_g, ln1_b, Abuf, rowbase);
    k_gemm_mfma<0><<<nMt * 6, 256, 0, stream>>>(Abuf, qkvT, qkv_b, Bbuf, 0, 768, 256, 6);
    k_attention<<<chw * 2, 256, 0, stream>>>(Bbuf, rpb, Cbuf);
    k_gemm_mfma<2><<<nMt * 2, 256, 0, stream>>>(Cbuf, projT, proj_b, tok, rowbase, 256, 256, 2);
    k_layernorm<false><<<chrows / 4, 256, 0, stream>>>(tok, ln2_g, ln2_b, Abuf, rowbase);
    k_gemm_mfma<1><<<nMt * 8, 256, 0, stream>>>(Abuf, fc1T, fc1_b, Bbuf, 0, 1024, 256, 8);
    k_gemm_mfma<3><<<nMt * 2, 256, 0, stream>>>(Bbuf, fc2T, fc2_b, tok, rowbase, 256, 1024, 2);
  }

  k_pool<<<BATCH, 256, 0, stream>>>(tok, pool);
  k_head<<<BATCH, 64, 0, stream>>>(pool, fco_w, fco_b, out);
}